// Round 3
// baseline (380.820 us; speedup 1.0000x reference)
//
#include <hip/hip_runtime.h>

// Problem constants (from reference)
#define BB 8
#define LL 4096
#define DIM 1024
#define HH 16
#define MM 64
#define DH 64

// Flat sizes / output offsets (outputs concatenated, read back as f32)
constexpr long long NZ = (long long)BB * LL * DIM;   // 33554432 (z_enforced / frozen_new)
constexpr long long NG = (long long)BB * LL * HH;    // 524288   (per-head scalars)
constexpr long long O_Z   = 0;
constexpr long long O_CRY = NZ;
constexpr long long O_NEW = NZ + NG;
constexpr long long O_CC  = NZ + 2 * NG;
constexpr long long O_FR  = NZ + 3 * NG;

// ---------------------------------------------------------------------------
// Pre-pass: detect whether `crystallised` is int32 {0,1} or packed uint8
// bools. OR the first NG/4 dwords (= all NG bytes if u8, first quarter if
// i32). u8 layout -> some high byte set -> OR > 1. i32 layout -> OR <= 1.
// ---------------------------------------------------------------------------
#define DETECT_BLOCKS 64
#define DETECT_DWORDS (NG / 4)

__global__ __launch_bounds__(256) void detect_bool_kernel(
    const unsigned int* __restrict__ buf, unsigned int* __restrict__ partials)
{
    __shared__ unsigned int acc;
    if (threadIdx.x == 0) acc = 0u;
    __syncthreads();
    const int per_block = DETECT_DWORDS / DETECT_BLOCKS;   // 2048
    const long long base = (long long)blockIdx.x * per_block;
    unsigned int v = 0u;
    for (int i = threadIdx.x; i < per_block; i += 256)
        v |= buf[base + i];
    atomicOr(&acc, v);
    __syncthreads();
    if (threadIdx.x == 0) partials[blockIdx.x] = acc;
}

// ---------------------------------------------------------------------------
// Main kernel: barrier-free, no LDS. grid 4096 x 256; each block processes
// ROWS consecutive (b,l) rows. Thread t owns float4 #t of the row; head
// h = t>>4 lives in 16 contiguous lanes of ONE wave (cross-lane via shfl).
// ---------------------------------------------------------------------------
#define ROWS 8

__global__ __launch_bounds__(256) void crystal_kernel(
    const float4* __restrict__ zc4,
    const float4* __restrict__ zp4,
    const float*  __restrict__ cb,     // [H][M][DH]
    const float4* __restrict__ fr4,
    const int*    __restrict__ ccount, // [B*L*H] int32
    const void*   __restrict__ cry_raw,
    const unsigned int* __restrict__ partials,
    float* __restrict__ out)
{
    const int t    = threadIdx.x;
    const int h    = t >> 4;
    const int sub  = t & 15;
    const int lane = t & 63;
    const int gb   = lane & ~15;       // 16-lane group base within the wave

    // crystallised layout mode (grid-uniform; scalar loads, L2-hot)
    unsigned int om = 0u;
    #pragma unroll
    for (int i = 0; i < DETECT_BLOCKS; ++i) om |= partials[i];
    const bool u8mode = om > 1u;

    const long long row0 = (long long)blockIdx.x * ROWS;
    long long idx = row0 * (DIM / 4) + t;

    float4 zc = zc4[idx];
    float4 zp = zp4[idx];
    float4 fr = fr4[idx];

    #pragma unroll 1
    for (int r = 0; r < ROWS; ++r) {
        // ---- prefetch next row while computing this one ----
        const long long nidx = idx + (DIM / 4);
        float4 zcn, zpn, frn;
        if (r < ROWS - 1) {
            zcn = zc4[nidx]; zpn = zp4[nidx]; frn = fr4[nidx];
        }

        const long long bl = row0 + r;
        const long long g  = bl * HH + h;

        // velocity^2: exact f32 diffs, f64 accumulate (order-independent to
        // ~1e-18 -> matches the f64 reference at the adversarial tau boundary)
        double s;
        {
            double dx = (double)zc.x - (double)zp.x;
            double dy = (double)zc.y - (double)zp.y;
            double dz = (double)zc.z - (double)zp.z;
            double dw = (double)zc.w - (double)zp.w;
            s = dx * dx + dy * dy + dz * dz + dw * dw;
        }
        s += __shfl_xor(s, 1);
        s += __shfl_xor(s, 2);
        s += __shfl_xor(s, 4);
        s += __shfl_xor(s, 8);

        const bool conv = sqrt(s) < 0.01;   // velocity < TAU_CONVERGE
        const int  cc   = ccount[g];
        const int  ccn  = conv ? cc + 1 : 0;
        const bool cry  = u8mode ? (((const unsigned char*)cry_raw)[g] != 0)
                                 : (((const int*)cry_raw)[g] != 0);
        const bool newly   = (ccn >= 2) && !cry;
        const bool crystal = cry || newly;

        float4 frout = fr;
        if (newly) {
            // argmin over M=64 codes of ||z - cb[h][m]||^2. `newly` is
            // group-uniform -> all 16 group lanes active -> shfl is safe.
            // Lane `sub` evaluates codes 4*sub..4*sub+3 (ascending -> first-min).
            const float* cbh = cb + (long long)h * MM * DH;
            double d2a[4] = {0.0, 0.0, 0.0, 0.0};
            #pragma unroll
            for (int k = 0; k < DH / 4; ++k) {
                float4 zk;
                zk.x = __shfl(zc.x, gb + k);
                zk.y = __shfl(zc.y, gb + k);
                zk.z = __shfl(zc.z, gb + k);
                zk.w = __shfl(zc.w, gb + k);
                #pragma unroll
                for (int mm = 0; mm < 4; ++mm) {
                    const float4 cv = reinterpret_cast<const float4*>(
                        cbh + (4 * sub + mm) * DH)[k];
                    double a = (double)zk.x - (double)cv.x;
                    double b = (double)zk.y - (double)cv.y;
                    double c = (double)zk.z - (double)cv.z;
                    double d = (double)zk.w - (double)cv.w;
                    d2a[mm] += a * a + b * b + c * c + d * d;
                }
            }
            double best = d2a[0];
            int bidx = 4 * sub;
            #pragma unroll
            for (int mm = 1; mm < 4; ++mm)
                if (d2a[mm] < best) { best = d2a[mm]; bidx = 4 * sub + mm; }
            #pragma unroll
            for (int mask = 1; mask <= 8; mask <<= 1) {
                double ob = __shfl_xor(best, mask);
                int    oi = __shfl_xor(bidx, mask);
                if (ob < best || (ob == best && oi < bidx)) { best = ob; bidx = oi; }
            }
            const float* erow = cbh + bidx * DH;
            frout.x = erow[4 * sub + 0];
            frout.y = erow[4 * sub + 1];
            frout.z = erow[4 * sub + 2];
            frout.w = erow[4 * sub + 3];
        }

        float4 zout;
        zout.x = crystal ? frout.x : zc.x;
        zout.y = crystal ? frout.y : zc.y;
        zout.z = crystal ? frout.z : zc.z;
        zout.w = crystal ? frout.w : zc.w;

        reinterpret_cast<float4*>(out + O_Z)[idx]  = zout;
        reinterpret_cast<float4*>(out + O_FR)[idx] = frout;
        if (sub == 0) {
            out[O_CRY + g] = crystal ? 1.0f : 0.0f;
            out[O_NEW + g] = newly   ? 1.0f : 0.0f;
            out[O_CC  + g] = (float)ccn;
        }

        zc = zcn; zp = zpn; fr = frn;
        idx = nidx;
    }
}

extern "C" void kernel_launch(void* const* d_in, const int* in_sizes, int n_in,
                              void* d_out, int out_size, void* d_ws, size_t ws_size,
                              hipStream_t stream) {
    const float4* zc4 = (const float4*)d_in[0];
    const float4* zp4 = (const float4*)d_in[1];
    const float*  cb  = (const float*)d_in[2];
    const float4* fr4 = (const float4*)d_in[3];
    const int*    cc  = (const int*)d_in[4];
    const void*   cry = d_in[5];
    float* out = (float*)d_out;
    unsigned int* partials = (unsigned int*)d_ws;   // 64 dwords of scratch

    hipLaunchKernelGGL(detect_bool_kernel, dim3(DETECT_BLOCKS), dim3(256), 0, stream,
                       (const unsigned int*)cry, partials);
    hipLaunchKernelGGL(crystal_kernel, dim3((BB * LL) / ROWS), dim3(256), 0, stream,
                       zc4, zp4, cb, fr4, cc, cry, partials, out);
}

// Round 4
// 218.626 us; speedup vs baseline: 1.7419x; 1.7419x over previous
//
#include <hip/hip_runtime.h>

// Problem constants (from reference)
#define BB 8
#define LL 4096
#define DIM 1024
#define HH 16
#define MM 64
#define DH 64

// Flat sizes / output offsets (outputs concatenated, read back as f32)
constexpr long long NZ = (long long)BB * LL * DIM;   // 33554432
constexpr long long NG = (long long)BB * LL * HH;    // 524288
constexpr long long O_Z   = 0;
constexpr long long O_CRY = NZ;
constexpr long long O_NEW = NZ + NG;
constexpr long long O_CC  = NZ + 2 * NG;
constexpr long long O_FR  = NZ + 3 * NG;

// ---------------------------------------------------------------------------
// Pre-pass: detect whether `crystallised` is int32 {0,1} or packed uint8
// bools. OR the first NG/4 dwords (= all NG bytes if u8, first quarter if
// i32). u8 layout -> some high byte set -> OR > 1. i32 layout -> OR <= 1.
// ---------------------------------------------------------------------------
#define DETECT_BLOCKS 64
#define DETECT_DWORDS (NG / 4)

__global__ __launch_bounds__(256) void detect_bool_kernel(
    const unsigned int* __restrict__ buf, unsigned int* __restrict__ partials)
{
    __shared__ unsigned int acc;
    if (threadIdx.x == 0) acc = 0u;
    __syncthreads();
    const int per_block = DETECT_DWORDS / DETECT_BLOCKS;   // 2048
    const long long base = (long long)blockIdx.x * per_block;
    unsigned int v = 0u;
    for (int i = threadIdx.x; i < per_block; i += 256)
        v |= buf[base + i];
    atomicOr(&acc, v);
    __syncthreads();
    if (threadIdx.x == 0) partials[blockIdx.x] = acc;
}

// ---------------------------------------------------------------------------
// Phase 1: pure streaming. velocity -> counters -> flags -> enforce with OLD
// frozen values. The codebook argmin is DEFERRED to crystal_snap (it was 41%
// of row-iterations streaming 64KB of 256B-stride codebook reads -> the R2
// bottleneck). For `newly` heads this writes a placeholder (old frozen);
// crystal_snap overwrites those 64-float segments afterwards.
// ---------------------------------------------------------------------------
#define ROWS 8

__global__ __launch_bounds__(256) void crystal_main(
    const float4* __restrict__ zc4,
    const float4* __restrict__ zp4,
    const float4* __restrict__ fr4,
    const int*    __restrict__ ccount, // [B*L*H] int32
    const void*   __restrict__ cry_raw,
    const unsigned int* __restrict__ partials,
    float* __restrict__ out)
{
    const int t   = threadIdx.x;
    const int h   = t >> 4;
    const int sub = t & 15;

    // crystallised layout mode (grid-uniform)
    unsigned int om = 0u;
    #pragma unroll
    for (int i = 0; i < DETECT_BLOCKS; ++i) om |= partials[i];
    const bool u8mode = om > 1u;

    const long long row0 = (long long)blockIdx.x * ROWS;
    long long idx = row0 * (DIM / 4) + t;
    long long g   = row0 * HH + h;

    float4 zc = zc4[idx];
    float4 zp = zp4[idx];
    float4 fr = fr4[idx];
    int    cc = ccount[g];
    int    cv = u8mode ? (int)((const unsigned char*)cry_raw)[g]
                       : ((const int*)cry_raw)[g];

    #pragma unroll 1
    for (int r = 0; r < ROWS; ++r) {
        // ---- prefetch next row while computing this one ----
        const long long nidx = idx + (DIM / 4);
        const long long gn   = g + HH;
        float4 zcn, zpn, frn; int ccn_ = 0, cvn = 0;
        if (r < ROWS - 1) {
            zcn = zc4[nidx]; zpn = zp4[nidx]; frn = fr4[nidx];
            ccn_ = ccount[gn];
            cvn  = u8mode ? (int)((const unsigned char*)cry_raw)[gn]
                          : ((const int*)cry_raw)[gn];
        }

        // velocity^2: exact f32 diffs, f64 accumulate (bit-identical to R2)
        double s;
        {
            double dx = (double)zc.x - (double)zp.x;
            double dy = (double)zc.y - (double)zp.y;
            double dz = (double)zc.z - (double)zp.z;
            double dw = (double)zc.w - (double)zp.w;
            s = dx * dx + dy * dy + dz * dz + dw * dw;
        }
        s += __shfl_xor(s, 1);
        s += __shfl_xor(s, 2);
        s += __shfl_xor(s, 4);
        s += __shfl_xor(s, 8);

        const bool conv = sqrt(s) < 0.01;   // velocity < TAU_CONVERGE
        const int  ccn  = conv ? cc + 1 : 0;
        const bool cry  = cv != 0;
        const bool newly   = (ccn >= 2) && !cry;
        const bool crystal = cry || newly;

        float4 zout;
        zout.x = crystal ? fr.x : zc.x;
        zout.y = crystal ? fr.y : zc.y;
        zout.z = crystal ? fr.z : zc.z;
        zout.w = crystal ? fr.w : zc.w;

        reinterpret_cast<float4*>(out + O_Z)[idx]  = zout;
        reinterpret_cast<float4*>(out + O_FR)[idx] = fr;
        if (sub == 0) {
            out[O_CRY + g] = crystal ? 1.0f : 0.0f;
            out[O_NEW + g] = newly   ? 1.0f : 0.0f;
            out[O_CC  + g] = (float)ccn;
        }

        zc = zcn; zp = zpn; fr = frn; cc = ccn_; cv = cvn;
        idx = nidx; g = gn;
    }
}

// ---------------------------------------------------------------------------
// Phase 2: codebook snap for `newly` heads only (~12.5% of heads).
// One 64-thread (1-wave) block per (head h, chunk of 64 rows); lane = code m.
// cb[h] (16KB) stays L1-resident across the block's ~8 newly rows; z row is
// LDS-staged and broadcast-read. f64 distance arithmetic expression-identical
// to the R2-passing kernel -> identical argmin decisions.
// ---------------------------------------------------------------------------
#define RPB 64
#define CHUNKS (BB * LL / RPB)   // 512

__global__ __launch_bounds__(64) void crystal_snap(
    const float4* __restrict__ zc4,
    const float*  __restrict__ cb,     // [H][M][DH]
    float* __restrict__ out)
{
    __shared__ float zsh[DH];

    const int lane = threadIdx.x;              // 0..63 = code index
    const int h    = blockIdx.x / CHUNKS;      // h-major: same-h blocks adjacent
    const int c    = blockIdx.x % CHUNKS;
    const long long blbase = (long long)c * RPB;

    // scan this chunk's newly flags for head h (written by crystal_main)
    const float f = out[O_NEW + (blbase + lane) * HH + h];
    unsigned long long mask = __ballot(f > 0.5f);
    if (mask == 0ull) return;

    const float* cbh = cb + (long long)h * MM * DH;
    const float4* crow = reinterpret_cast<const float4*>(cbh + lane * DH);

    while (mask) {
        const int r = __ffsll(mask) - 1;
        mask &= mask - 1;
        const long long bl   = blbase + r;
        const long long seg4 = bl * (DIM / 4) + h * (DH / 4);

        if (lane < 16)
            reinterpret_cast<float4*>(zsh)[lane] = zc4[seg4 + lane];
        __syncthreads();

        double d2 = 0.0;
        #pragma unroll
        for (int k = 0; k < DH / 4; ++k) {
            const float4 zk = reinterpret_cast<const float4*>(zsh)[k]; // broadcast
            const float4 cvv = crow[k];
            double a = (double)zk.x - (double)cvv.x;
            double b = (double)zk.y - (double)cvv.y;
            double cq = (double)zk.z - (double)cvv.z;
            double d = (double)zk.w - (double)cvv.w;
            d2 += a * a + b * b + cq * cq + d * d;
        }

        double best = d2;
        int bidx = lane;
        #pragma unroll
        for (int m2 = 1; m2 <= 32; m2 <<= 1) {
            double ob = __shfl_xor(best, m2);
            int    oi = __shfl_xor(bidx, m2);
            if (ob < best || (ob == best && oi < bidx)) { best = ob; bidx = oi; }
        }

        if (lane < 16) {
            const float4 ev = reinterpret_cast<const float4*>(cbh + bidx * DH)[lane];
            reinterpret_cast<float4*>(out + O_Z)[seg4 + lane]  = ev;
            reinterpret_cast<float4*>(out + O_FR)[seg4 + lane] = ev;
        }
        __syncthreads();   // zsh safe to overwrite next iteration
    }
}

extern "C" void kernel_launch(void* const* d_in, const int* in_sizes, int n_in,
                              void* d_out, int out_size, void* d_ws, size_t ws_size,
                              hipStream_t stream) {
    const float4* zc4 = (const float4*)d_in[0];
    const float4* zp4 = (const float4*)d_in[1];
    const float*  cb  = (const float*)d_in[2];
    const float4* fr4 = (const float4*)d_in[3];
    const int*    cc  = (const int*)d_in[4];
    const void*   cry = d_in[5];
    float* out = (float*)d_out;
    unsigned int* partials = (unsigned int*)d_ws;   // 64 dwords of scratch

    hipLaunchKernelGGL(detect_bool_kernel, dim3(DETECT_BLOCKS), dim3(256), 0, stream,
                       (const unsigned int*)cry, partials);
    hipLaunchKernelGGL(crystal_main, dim3((BB * LL) / ROWS), dim3(256), 0, stream,
                       zc4, zp4, fr4, cc, cry, partials, out);
    hipLaunchKernelGGL(crystal_snap, dim3(HH * CHUNKS), dim3(64), 0, stream,
                       zc4, cb, out);
}